// Round 9
// baseline (173.435 us; speedup 1.0000x reference)
//
#include <hip/hip_runtime.h>
#include <math.h>

#define L_SEQ 1024
#define TOPK 6
#define SSTR 1057   // per-seq LDS plane stride (floats): 32*33+1 -> bank skew
#define NFBLK 512   // fft blocks (one (b,h,ehalf) each, 4 e-chunks of 8)

// W32^m = e^{-2*pi*i*m/32}, compile-time constants
__device__ constexpr float TW32R[16] = {
  1.f, 0.98078528f, 0.92387953f, 0.83146961f, 0.70710678f, 0.55557023f,
  0.38268343f, 0.19509032f, 0.f, -0.19509032f, -0.38268343f, -0.55557023f,
  -0.70710678f, -0.83146961f, -0.92387953f, -0.98078528f};
__device__ constexpr float TW32I[16] = {
  0.f, -0.19509032f, -0.38268343f, -0.55557023f, -0.70710678f, -0.83146961f,
  -0.92387953f, -0.98078528f, -1.f, -0.98078528f, -0.92387953f, -0.83146961f,
  -0.70710678f, -0.55557023f, -0.38268343f, -0.19509032f};

// radix-2 DIT stage; m_==0 / m_==8 (W=1 / W=-i) fold to add/swap at compile
// time (unrolled, constant branch).
#define FFTSTAGE(M, H, SH)                                                \
  _Pragma("unroll")                                                       \
  for (int k_ = 0; k_ < 32; k_ += (M)) {                                  \
    _Pragma("unroll")                                                     \
    for (int t_ = 0; t_ < (H); ++t_) {                                    \
      const int a_ = k_ + t_, b_ = a_ + (H);                              \
      const int m_ = t_ << (SH);                                          \
      float vr_, vi_;                                                     \
      if (m_ == 0)      { vr_ = zr[b_]; vi_ = zi[b_]; }                   \
      else if (m_ == 8) { vr_ = zi[b_]; vi_ = -zr[b_]; }                  \
      else {                                                              \
        vr_ = zr[b_] * TW32R[m_] - zi[b_] * TW32I[m_];                    \
        vi_ = zr[b_] * TW32I[m_] + zi[b_] * TW32R[m_];                    \
      }                                                                   \
      zr[b_] = zr[a_] - vr_; zi[b_] = zi[a_] - vi_;                       \
      zr[a_] += vr_;         zi[a_] += vi_;                               \
    }                                                                     \
  }

// ---------------------------------------------------------------------------
// Kernel 1: packed complex FFT + cross-spectrum partials.
// Block = one (b, h, e-half of 32); 4 sequential chunks of 8 seqs
// z = q[b,:,h,e] + i*k[b,:,h,e]. 1024-pt FFT via four-step (FFT32 x2 +
// column twiddle). Real-split pairing:
//   S[j] = Qf[j]*conj(Kf[j]) = 0.5*Im(A*P) + i*0.25*(|A|^2-|P|^2),
//   A = Z[j], P = Z[1024-j].
// Per-block partial spectrum accumulated in regs over 4 chunks ->
// partial[bid][2048] (Re 0..1023, Im 1024..2047).
// ---------------------------------------------------------------------------
__global__ __launch_bounds__(256, 4) void fft_spec_kernel(
    const float* __restrict__ q, const float* __restrict__ k,
    float* __restrict__ partial)
{
  __shared__ float pr[8 * SSTR];
  __shared__ float pim[8 * SSTR];

  const int tid = threadIdx.x;

  // XCD-chunked bijective swizzle: 512 blocks, 64 consecutive works per XCD
  // (a 64-work chunk = 4 complete batches -> full q/k row reuse in its L2)
  const int bid   = blockIdx.x;
  const int work  = (bid & 7) * 64 + (bid >> 3);
  const int ehalf = work & 1;
  const int h     = (work >> 1) & 7;
  const int b     = work >> 4;

  const int s = tid >> 5;     // sequence within chunk (0..7)
  const int i = tid & 31;     // lane within sequence
  constexpr int BR[32] = {0,16,8,24,4,20,12,28,2,18,10,26,6,22,14,30,
                          1,17,9,25,5,21,13,29,3,19,11,27,7,23,15,31};

  const float astep = (float)i * 6.13592315e-03f;   // 2*pi*i/1024

  const float* qb = q + (size_t)b * 524288 + h * 64 + ehalf * 32;
  const float* kb = k + (size_t)b * 524288 + h * 64 + ehalf * 32;

  // stage addressing: lane covers 4 e's of a row; 128 rows per iter
  const int ep  = (tid & 1) * 4;
  const int lb  = tid >> 1;                         // 0..127
  const int col0 = (lb & 31) * 33 + (lb >> 5);      // col = col0 + it*4

  float srac[4] = {0.f, 0.f, 0.f, 0.f};
  float siac[4] = {0.f, 0.f, 0.f, 0.f};
  float zr[32], zi[32];

  for (int ch = 0; ch < 4; ++ch) {
    const int e0 = ch * 8;

    __syncthreads();   // previous chunk's plane reads done
    // ---- stage: float4 loads, scalar LDS writes (2-way max) ----
    #pragma unroll
    for (int it = 0; it < 8; ++it) {
      const int l = it * 128 + lb;
      const float4 qv = *(const float4*)(qb + l * 512 + e0 + ep);
      const float4 kv = *(const float4*)(kb + l * 512 + e0 + ep);
      const int col = col0 + it * 4;
      pr[(ep + 0) * SSTR + col] = qv.x;
      pr[(ep + 1) * SSTR + col] = qv.y;
      pr[(ep + 2) * SSTR + col] = qv.z;
      pr[(ep + 3) * SSTR + col] = qv.w;
      pim[(ep + 0) * SSTR + col] = kv.x;
      pim[(ep + 1) * SSTR + col] = kv.y;
      pim[(ep + 2) * SSTR + col] = kv.z;
      pim[(ep + 3) * SSTR + col] = kv.w;
    }
    __syncthreads();

    // ---- phase 1: FFT32 over n2 (own row), column twiddle, write back ----
    {
      const int rowbase = s * SSTR + i * 33;
      #pragma unroll
      for (int p = 0; p < 32; ++p) {
        zr[p] = pr[rowbase + BR[p]];
        zi[p] = pim[rowbase + BR[p]];
      }
      FFTSTAGE(2, 1, 4) FFTSTAGE(4, 2, 3) FFTSTAGE(8, 4, 2)
      FFTSTAGE(16, 8, 1) FFTSTAGE(32, 16, 0)
      // W1024^{i*k2}: independent fast sincos per k2
      #pragma unroll
      for (int k2 = 0; k2 < 32; ++k2) {
        if (k2 == 0) {
          pr[rowbase]  = zr[0];
          pim[rowbase] = zi[0];
        } else {
          float sa, ca;
          __sincosf(astep * (float)k2, &sa, &ca);
          pr[rowbase + k2]  = zr[k2] * ca + zi[k2] * sa;
          pim[rowbase + k2] = zi[k2] * ca - zr[k2] * sa;
        }
      }
    }
    __syncthreads();

    // ---- phase 2: FFT32 over n1 (own column j = i) ----
    const int j = i;
    #pragma unroll
    for (int p = 0; p < 32; ++p) {
      zr[p] = pr[s * SSTR + BR[p] * 33 + j];
      zi[p] = pim[s * SSTR + BR[p] * 33 + j];
    }
    __syncthreads();            // column reads done before row writes
    FFTSTAGE(2, 1, 4) FFTSTAGE(4, 2, 3) FFTSTAGE(8, 4, 2)
    FFTSTAGE(16, 8, 1) FFTSTAGE(32, 16, 0)
    // publish rows: Z[32*k1 + j]
    #pragma unroll
    for (int k1 = 0; k1 < 32; ++k1) {
      pr[s * SSTR + j * 33 + k1]  = zr[k1];
      pim[s * SSTR + j * 33 + k1] = zi[k1];
    }
    __syncthreads();

    // ---- pairing: S[32k1+j] from A = Z[bin], P = Z[1024-bin] ----
    {
      const int prow = (32 - j) & 31;
      #pragma unroll
      for (int k1 = 0; k1 < 32; ++k1) {
        const int pcol = j ? (31 - k1) : ((32 - k1) & 31);
        const float prr = pr[s * SSTR + prow * 33 + pcol];
        const float pii = pim[s * SSTR + prow * 33 + pcol];
        const float ar = zr[k1], ai = zi[k1];
        zr[k1] = 0.5f * (ar * pii + ai * prr);                        // Re S
        zi[k1] = 0.25f * (ar * ar + ai * ai - prr * prr - pii * pii); // Im S
      }
    }
    __syncthreads();            // pairing reads done before overwrite
    #pragma unroll
    for (int k1 = 0; k1 < 32; ++k1) {
      pr[s * SSTR + j * 33 + k1]  = zr[k1];
      pim[s * SSTR + j * 33 + k1] = zi[k1];
    }
    __syncthreads();

    // ---- accumulate 8-seq reduction into registers ----
    #pragma unroll
    for (int u = 0; u < 4; ++u) {
      const int bin = u * 256 + tid;
      const int jj = bin & 31, kk = bin >> 5;
      float sr = 0.f, si = 0.f;
      #pragma unroll
      for (int s2 = 0; s2 < 8; ++s2) {
        sr += pr[s2 * SSTR + jj * 33 + kk];
        si += pim[s2 * SSTR + jj * 33 + kk];
      }
      srac[u] += sr;
      siac[u] += si;
    }
  }

  #pragma unroll
  for (int u = 0; u < 4; ++u) {
    const int bin = u * 256 + tid;
    partial[(size_t)bid * 2048 + bin]        = srac[u];
    partial[(size_t)bid * 2048 + 1024 + bin] = siac[u];
  }
}

// ---------------------------------------------------------------------------
// Kernel 2: S[v] = sum_{r<512} partial[r][v].  grid 32 x 256.
// ---------------------------------------------------------------------------
__global__ __launch_bounds__(256) void spec_reduce(
    const float* __restrict__ partial, float* __restrict__ S)
{
  const int t = threadIdx.x;
  const int b64 = t & 63, rc = t >> 6;
  const int v = blockIdx.x * 64 + b64;
  float acc = 0.f;
  for (int rr = rc * 128; rr < rc * 128 + 128; ++rr)
    acc += partial[(size_t)rr * 2048 + v];
  __shared__ float sm[4][65];
  sm[rc][b64] = acc;
  __syncthreads();
  if (t < 64)
    S[v] = sm[0][t] + sm[1][t] + sm[2][t] + sm[3][t];
}

// ---------------------------------------------------------------------------
// Kernel 3: c[tau] = (1/(1024*16384)) * sum_j Re(S[j] e^{+2pi i j tau/1024})
// grid 32 x 256: 32 taus per block, 8 j-chunks of 128.
// ---------------------------------------------------------------------------
__global__ __launch_bounds__(256) void corr_kernel(
    const float* __restrict__ S, float* __restrict__ c)
{
  __shared__ float sm[8][33];
  const int t = threadIdx.x;
  const int tau = blockIdx.x * 32 + (t & 31);
  const int jc = t >> 5;
  float acc = 0.f;
  #pragma unroll 4
  for (int jj = 0; jj < 128; ++jj) {
    const int j = jc * 128 + jj;
    float s_, c_;
    __sincosf((float)((j * tau) & 1023) * 6.13592315e-03f, &s_, &c_);
    acc += S[j] * c_ - S[1024 + j] * s_;
  }
  sm[jc][t & 31] = acc;
  __syncthreads();
  if (t < 32) {
    float r = 0.f;
    #pragma unroll
    for (int g = 0; g < 8; ++g) r += sm[g][t];
    c[blockIdx.x * 32 + t] = r * (1.0f / 16777216.0f);
  }
}

// ---------------------------------------------------------------------------
// Kernel 4: top-6 (desc, smaller-index tie-break) + softmax. 1 block.
// ---------------------------------------------------------------------------
__global__ __launch_bounds__(256) void topk_kernel(
    const float* __restrict__ c, int* __restrict__ idx_out,
    float* __restrict__ w_out)
{
  __shared__ float vals[L_SEQ];
  __shared__ float rv[256];
  __shared__ int ri[256];
  __shared__ float topv[TOPK];
  __shared__ int topi[TOPK];
  const int tid = threadIdx.x;
  for (int i = tid; i < L_SEQ; i += 256) vals[i] = c[i];
  __syncthreads();

  for (int kk = 0; kk < TOPK; ++kk) {
    float bv = -INFINITY;
    int bi = 1 << 30;
    for (int i = tid; i < L_SEQ; i += 256) {
      const float v = vals[i];
      if (v > bv || (v == bv && i < bi)) { bv = v; bi = i; }
    }
    rv[tid] = bv; ri[tid] = bi;
    __syncthreads();
    for (int off = 128; off > 0; off >>= 1) {
      if (tid < off) {
        const float v2 = rv[tid + off];
        const int i2 = ri[tid + off];
        if (v2 > rv[tid] || (v2 == rv[tid] && i2 < ri[tid])) {
          rv[tid] = v2; ri[tid] = i2;
        }
      }
      __syncthreads();
    }
    if (tid == 0) {
      topv[kk] = rv[0];
      topi[kk] = ri[0];
      vals[ri[0]] = -INFINITY;
    }
    __syncthreads();
  }

  if (tid == 0) {
    const float m = topv[0];
    float e[TOPK], sum = 0.f;
    for (int i = 0; i < TOPK; ++i) { e[i] = expf(topv[i] - m); sum += e[i]; }
    const float inv = 1.0f / sum;
    for (int i = 0; i < TOPK; ++i) { w_out[i] = e[i] * inv; idx_out[i] = topi[i]; }
  }
}

// ---------------------------------------------------------------------------
// Kernel 5: out[b,l,h,e] = sum_k w[k] * v[b,(l+idx[k])%L,h,e]
// ---------------------------------------------------------------------------
__global__ __launch_bounds__(256) void agg_kernel(
    const float* __restrict__ v, const int* __restrict__ idx,
    const float* __restrict__ w, float4* __restrict__ out)
{
  __shared__ int sidx[TOPK];
  __shared__ float sw[TOPK];
  if (threadIdx.x < TOPK) {
    sidx[threadIdx.x] = idx[threadIdx.x];
    sw[threadIdx.x] = w[threadIdx.x];
  }
  __syncthreads();

  const int i = blockIdx.x * 256 + threadIdx.x;   // 0 .. 2^22-1
  const int he4 = i & 127;
  const int l = (i >> 7) & (L_SEQ - 1);
  const int b = i >> 17;
  const float4* vb = (const float4*)v + (size_t)b * (L_SEQ * 128);

  float4 acc = make_float4(0.f, 0.f, 0.f, 0.f);
  #pragma unroll
  for (int kk = 0; kk < TOPK; ++kk) {
    const int src = (l + sidx[kk]) & (L_SEQ - 1);
    const float4 vv = vb[(size_t)src * 128 + he4];
    const float wk = sw[kk];
    acc.x += wk * vv.x; acc.y += wk * vv.y;
    acc.z += wk * vv.z; acc.w += wk * vv.w;
  }
  out[i] = acc;
}

// ---------------------------------------------------------------------------
extern "C" void kernel_launch(void* const* d_in, const int* in_sizes, int n_in,
                              void* d_out, int out_size, void* d_ws, size_t ws_size,
                              hipStream_t stream) {
  const float* q = (const float*)d_in[0];
  const float* k = (const float*)d_in[1];
  const float* v = (const float*)d_in[2];
  // d_in[3] = attn_mask (scalar 0) -- unused

  float* out = (float*)d_out;
  // scratch inside d_out (consumed before agg overwrites):
  //   partial: 512 x 2048 floats (4 MB) at out[0]
  float* partial = out;

  float* c    = (float*)d_ws;                          // 1024 floats
  int*   idxp = (int*)((char*)d_ws + 4096);            // 6 ints
  float* wp   = (float*)((char*)d_ws + 4096 + 64);     // 6 floats
  float* S    = (float*)((char*)d_ws + 8192);          // 2048 floats

  fft_spec_kernel<<<NFBLK, 256, 0, stream>>>(q, k, partial);
  spec_reduce<<<32, 256, 0, stream>>>(partial, S);
  corr_kernel<<<32, 256, 0, stream>>>(S, c);
  topk_kernel<<<1, 256, 0, stream>>>(c, idxp, wp);
  agg_kernel<<<(L_SEQ * 32 * 128) / 256, 256, 0, stream>>>(v, idxp, wp,
                                                           (float4*)out);
}

// Round 10
// 124.531 us; speedup vs baseline: 1.3927x; 1.3927x over previous
//
#include <hip/hip_runtime.h>
#include <math.h>

#define L_SEQ 1024
#define TOPK 6
#define SSTR 1057   // per-seq LDS plane stride (floats): 32*33+1 -> bank skew
#define NFBLK 2048  // one (b,h,e-octet) per block

// W32^m = e^{-2*pi*i*m/32}, compile-time constants
__device__ constexpr float TW32R[16] = {
  1.f, 0.98078528f, 0.92387953f, 0.83146961f, 0.70710678f, 0.55557023f,
  0.38268343f, 0.19509032f, 0.f, -0.19509032f, -0.38268343f, -0.55557023f,
  -0.70710678f, -0.83146961f, -0.92387953f, -0.98078528f};
__device__ constexpr float TW32I[16] = {
  0.f, -0.19509032f, -0.38268343f, -0.55557023f, -0.70710678f, -0.83146961f,
  -0.92387953f, -0.98078528f, -1.f, -0.98078528f, -0.92387953f, -0.83146961f,
  -0.70710678f, -0.55557023f, -0.38268343f, -0.19509032f};

// radix-2 DIT stage; m_==0 / m_==8 (W=1 / W=-i) fold at compile time.
#define FFTSTAGE(M, H, SH)                                                \
  _Pragma("unroll")                                                       \
  for (int k_ = 0; k_ < 32; k_ += (M)) {                                  \
    _Pragma("unroll")                                                     \
    for (int t_ = 0; t_ < (H); ++t_) {                                    \
      const int a_ = k_ + t_, b_ = a_ + (H);                              \
      const int m_ = t_ << (SH);                                          \
      float vr_, vi_;                                                     \
      if (m_ == 0)      { vr_ = zr[b_]; vi_ = zi[b_]; }                   \
      else if (m_ == 8) { vr_ = zi[b_]; vi_ = -zr[b_]; }                  \
      else {                                                              \
        vr_ = zr[b_] * TW32R[m_] - zi[b_] * TW32I[m_];                    \
        vi_ = zr[b_] * TW32I[m_] + zi[b_] * TW32R[m_];                    \
      }                                                                   \
      zr[b_] = zr[a_] - vr_; zi[b_] = zi[a_] - vi_;                       \
      zr[a_] += vr_;         zi[a_] += vi_;                               \
    }                                                                     \
  }

// ---------------------------------------------------------------------------
// Kernel 1: packed complex FFT + cross-spectrum partials.
// Block = one (b, h, e-octet): 8 seqs z = q[b,:,h,e] + i*k[b,:,h,e].
// 1024-pt FFT via four-step (FFT32 rows -> column twiddle -> FFT32 cols).
// Pairing S[j] = Qf[j]*conj(Kf[j]) = 0.5*Im(A*P) + i*0.25*(|A|^2-|P|^2),
// A = Z[bin], P = Z[1024-bin], done IN-REGISTER via __shfl (partner lane
// (32-j)&31, reg 31-k1; j==0 self-case uses local reg (32-k1)&31).
// Work decode pairs adjacent dispatch ids to the two e-octets of one 64-B
// HBM granule (overfetch fix). 4 barriers total.
// ---------------------------------------------------------------------------
__global__ __launch_bounds__(256, 2) void fft_spec_kernel(
    const float* __restrict__ q, const float* __restrict__ k,
    float* __restrict__ partial)
{
  __shared__ float pr[8 * SSTR];   // 33.8 KB
  __shared__ float pim[8 * SSTR];  // 33.8 KB

  const int tid = threadIdx.x;
  const int bid = blockIdx.x;

  // work decode: bid&7 spreads XCDs; within an XCD chunk, consecutive wq =
  // octet pair of one 64-B granule (co-resident -> L2 line shared), then
  // granule, then h, then b.
  const int wq  = bid >> 3;                  // 0..255
  const int xcd = bid & 7;
  const int octet = (wq & 1) | (((wq >> 1) & 3) << 1);
  const int h = (wq >> 3) & 7;
  const int b = (xcd << 2) | (wq >> 6);

  const float* qb = q + (size_t)b * 524288 + h * 64 + octet * 8;
  const float* kb = k + (size_t)b * 524288 + h * 64 + octet * 8;

  // ---- stage: float4 loads; element l of seq e -> plane[e*SSTR + col(l)],
  // col(l) = (l&31)*33 + (l>>5)  (transposed, bank-skewed) ----
  {
    const int ep = (tid & 1) * 4;
    const int lb = tid >> 1;                       // 0..127
    const int col0 = (lb & 31) * 33 + (lb >> 5);
    #pragma unroll
    for (int it = 0; it < 8; ++it) {
      const int l = it * 128 + lb;
      const float4 qv = *(const float4*)(qb + (size_t)l * 512 + ep);
      const float4 kv = *(const float4*)(kb + (size_t)l * 512 + ep);
      const int col = col0 + it * 4;
      pr[(ep + 0) * SSTR + col] = qv.x;
      pr[(ep + 1) * SSTR + col] = qv.y;
      pr[(ep + 2) * SSTR + col] = qv.z;
      pr[(ep + 3) * SSTR + col] = qv.w;
      pim[(ep + 0) * SSTR + col] = kv.x;
      pim[(ep + 1) * SSTR + col] = kv.y;
      pim[(ep + 2) * SSTR + col] = kv.z;
      pim[(ep + 3) * SSTR + col] = kv.w;
    }
  }
  __syncthreads();

  const int s = tid >> 5;     // sequence (0..7)
  const int i = tid & 31;     // lane within sequence
  constexpr int BR[32] = {0,16,8,24,4,20,12,28,2,18,10,26,6,22,14,30,
                          1,17,9,25,5,21,13,29,3,19,11,27,7,23,15,31};
  const float astep = (float)i * 6.13592315e-03f;   // 2*pi*i/1024
  float zr[32], zi[32];

  // ---- phase 1: FFT32 over n2 (own row), column twiddle, write back ----
  {
    const int rowbase = s * SSTR + i * 33;
    #pragma unroll
    for (int p = 0; p < 32; ++p) {
      zr[p] = pr[rowbase + BR[p]];
      zi[p] = pim[rowbase + BR[p]];
    }
    FFTSTAGE(2, 1, 4) FFTSTAGE(4, 2, 3) FFTSTAGE(8, 4, 2)
    FFTSTAGE(16, 8, 1) FFTSTAGE(32, 16, 0)
    #pragma unroll
    for (int k2 = 0; k2 < 32; ++k2) {
      if (k2 == 0) {
        pr[rowbase]  = zr[0];
        pim[rowbase] = zi[0];
      } else {
        float sa, ca;
        __sincosf(astep * (float)k2, &sa, &ca);
        pr[rowbase + k2]  = zr[k2] * ca + zi[k2] * sa;
        pim[rowbase + k2] = zi[k2] * ca - zr[k2] * sa;
      }
    }
  }
  __syncthreads();

  // ---- phase 2: FFT32 over n1 (own column j = i); result stays in regs ----
  const int j = i;
  #pragma unroll
  for (int p = 0; p < 32; ++p) {
    zr[p] = pr[s * SSTR + BR[p] * 33 + j];
    zi[p] = pim[s * SSTR + BR[p] * 33 + j];
  }
  __syncthreads();            // all column reads done before S overwrites
  FFTSTAGE(2, 1, 4) FFTSTAGE(4, 2, 3) FFTSTAGE(8, 4, 2)
  FFTSTAGE(16, 8, 1) FFTSTAGE(32, 16, 0)
  // lane j holds Z[32*k1 + j] in (zr[k1], zi[k1])

  // ---- pairing via in-wave shfl; write S rows directly ----
  {
    const int t64 = tid & 63;
    const int pl = (t64 & 32) | ((32 - j) & 31);   // partner lane in wave
    #pragma unroll
    for (int k1 = 0; k1 < 32; ++k1) {
      float xr = __shfl(zr[31 - k1], pl, 64);
      float xi = __shfl(zi[31 - k1], pl, 64);
      if (j == 0) { xr = zr[(32 - k1) & 31]; xi = zi[(32 - k1) & 31]; }
      const float ar = zr[k1], ai = zi[k1];
      pr [s * SSTR + j * 33 + k1] = 0.5f  * (ar * xi + ai * xr);
      pim[s * SSTR + j * 33 + k1] = 0.25f * (ar * ar + ai * ai
                                             - xr * xr - xi * xi);
    }
  }
  __syncthreads();

  // ---- reduce 8 seqs -> partial[bid][2048] (Re 0..1023, Im 1024..2047) ----
  #pragma unroll
  for (int u = 0; u < 8; ++u) {
    const int bin = u * 256 + tid;
    const int bb = bin & 1023;
    const int jj = bb & 31, kk = bb >> 5;
    const float* pl_ = (u >= 4) ? pim : pr;
    float acc = 0.f;
    #pragma unroll
    for (int s2 = 0; s2 < 8; ++s2) acc += pl_[s2 * SSTR + jj * 33 + kk];
    partial[(size_t)bid * 2048 + bin] = acc;
  }
}

// ---------------------------------------------------------------------------
// Kernel 2: S[v] = sum_{r<2048} partial[r][v].  grid 32 x 256.
// ---------------------------------------------------------------------------
__global__ __launch_bounds__(256) void spec_reduce(
    const float* __restrict__ partial, float* __restrict__ S)
{
  const int t = threadIdx.x;
  const int b64 = t & 63, rc = t >> 6;
  const int v = blockIdx.x * 64 + b64;
  float acc = 0.f;
  for (int rr = rc * 512; rr < rc * 512 + 512; ++rr)
    acc += partial[(size_t)rr * 2048 + v];
  __shared__ float sm[4][65];
  sm[rc][b64] = acc;
  __syncthreads();
  if (t < 64)
    S[v] = sm[0][t] + sm[1][t] + sm[2][t] + sm[3][t];
}

// ---------------------------------------------------------------------------
// Kernel 3: c[tau] = (1/(1024*16384)) * sum_j Re(S[j] e^{+2pi i j tau/1024})
// ---------------------------------------------------------------------------
__global__ __launch_bounds__(256) void corr_kernel(
    const float* __restrict__ S, float* __restrict__ c)
{
  __shared__ float sm[8][33];
  const int t = threadIdx.x;
  const int tau = blockIdx.x * 32 + (t & 31);
  const int jc = t >> 5;
  float acc = 0.f;
  #pragma unroll 4
  for (int jj = 0; jj < 128; ++jj) {
    const int j = jc * 128 + jj;
    float s_, c_;
    __sincosf((float)((j * tau) & 1023) * 6.13592315e-03f, &s_, &c_);
    acc += S[j] * c_ - S[1024 + j] * s_;
  }
  sm[jc][t & 31] = acc;
  __syncthreads();
  if (t < 32) {
    float r = 0.f;
    #pragma unroll
    for (int g = 0; g < 8; ++g) r += sm[g][t];
    c[blockIdx.x * 32 + t] = r * (1.0f / 16777216.0f);
  }
}

// ---------------------------------------------------------------------------
// Kernel 4: top-6 (desc, smaller-index tie-break) + softmax. 1 block.
// ---------------------------------------------------------------------------
__global__ __launch_bounds__(256) void topk_kernel(
    const float* __restrict__ c, int* __restrict__ idx_out,
    float* __restrict__ w_out)
{
  __shared__ float vals[L_SEQ];
  __shared__ float rv[256];
  __shared__ int ri[256];
  __shared__ float topv[TOPK];
  __shared__ int topi[TOPK];
  const int tid = threadIdx.x;
  for (int i = tid; i < L_SEQ; i += 256) vals[i] = c[i];
  __syncthreads();

  for (int kk = 0; kk < TOPK; ++kk) {
    float bv = -INFINITY;
    int bi = 1 << 30;
    for (int i = tid; i < L_SEQ; i += 256) {
      const float v = vals[i];
      if (v > bv || (v == bv && i < bi)) { bv = v; bi = i; }
    }
    rv[tid] = bv; ri[tid] = bi;
    __syncthreads();
    for (int off = 128; off > 0; off >>= 1) {
      if (tid < off) {
        const float v2 = rv[tid + off];
        const int i2 = ri[tid + off];
        if (v2 > rv[tid] || (v2 == rv[tid] && i2 < ri[tid])) {
          rv[tid] = v2; ri[tid] = i2;
        }
      }
      __syncthreads();
    }
    if (tid == 0) {
      topv[kk] = rv[0];
      topi[kk] = ri[0];
      vals[ri[0]] = -INFINITY;
    }
    __syncthreads();
  }

  if (tid == 0) {
    const float m = topv[0];
    float e[TOPK], sum = 0.f;
    for (int i = 0; i < TOPK; ++i) { e[i] = expf(topv[i] - m); sum += e[i]; }
    const float inv = 1.0f / sum;
    for (int i = 0; i < TOPK; ++i) { w_out[i] = e[i] * inv; idx_out[i] = topi[i]; }
  }
}

// ---------------------------------------------------------------------------
// Kernel 5: out[b,l,h,e] = sum_k w[k] * v[b,(l+idx[k])%L,h,e]
// ---------------------------------------------------------------------------
__global__ __launch_bounds__(256) void agg_kernel(
    const float* __restrict__ v, const int* __restrict__ idx,
    const float* __restrict__ w, float4* __restrict__ out)
{
  __shared__ int sidx[TOPK];
  __shared__ float sw[TOPK];
  if (threadIdx.x < TOPK) {
    sidx[threadIdx.x] = idx[threadIdx.x];
    sw[threadIdx.x] = w[threadIdx.x];
  }
  __syncthreads();

  const int i = blockIdx.x * 256 + threadIdx.x;   // 0 .. 2^22-1
  const int he4 = i & 127;
  const int l = (i >> 7) & (L_SEQ - 1);
  const int b = i >> 17;
  const float4* vb = (const float4*)v + (size_t)b * (L_SEQ * 128);

  float4 acc = make_float4(0.f, 0.f, 0.f, 0.f);
  #pragma unroll
  for (int kk = 0; kk < TOPK; ++kk) {
    const int src = (l + sidx[kk]) & (L_SEQ - 1);
    const float4 vv = vb[(size_t)src * 128 + he4];
    const float wk = sw[kk];
    acc.x += wk * vv.x; acc.y += wk * vv.y;
    acc.z += wk * vv.z; acc.w += wk * vv.w;
  }
  out[i] = acc;
}

// ---------------------------------------------------------------------------
extern "C" void kernel_launch(void* const* d_in, const int* in_sizes, int n_in,
                              void* d_out, int out_size, void* d_ws, size_t ws_size,
                              hipStream_t stream) {
  const float* q = (const float*)d_in[0];
  const float* k = (const float*)d_in[1];
  const float* v = (const float*)d_in[2];
  // d_in[3] = attn_mask (scalar 0) -- unused

  float* out = (float*)d_out;
  // scratch inside d_out (consumed before agg overwrites):
  //   partial: 2048 x 2048 floats (16 MB) at out[0]
  float* partial = out;

  float* c    = (float*)d_ws;                          // 1024 floats
  int*   idxp = (int*)((char*)d_ws + 4096);            // 6 ints
  float* wp   = (float*)((char*)d_ws + 4096 + 64);     // 6 floats
  float* S    = (float*)((char*)d_ws + 8192);          // 2048 floats

  fft_spec_kernel<<<NFBLK, 256, 0, stream>>>(q, k, partial);
  spec_reduce<<<32, 256, 0, stream>>>(partial, S);
  corr_kernel<<<32, 256, 0, stream>>>(S, c);
  topk_kernel<<<1, 256, 0, stream>>>(c, idxp, wp);
  agg_kernel<<<(L_SEQ * 32 * 128) / 256, 256, 0, stream>>>(v, idxp, wp,
                                                           (float4*)out);
}